// Round 21
// baseline (85.816 us; speedup 1.0000x reference)
//
#include <hip/hip_runtime.h>

#define DIN 2048
#define WPR 64            // u32 words per row (2048 bits)
#define QPR 32            // u64 words per row
#define GPR 16            // 16B granules per row
#define RPB 8             // rows per expand block
#define LN_EPS 1e-5f

#define GLOBAL_AS __attribute__((address_space(1)))
#define LDS_AS    __attribute__((address_space(3)))

typedef unsigned long long u64;
typedef int   i32x4  __attribute__((ext_vector_type(4)));
typedef int   i32x8  __attribute__((ext_vector_type(8)));
typedef float f32x16 __attribute__((ext_vector_type(16)));

__device__ inline float wave_sum(float v) {
    #pragma unroll
    for (int off = 32; off; off >>= 1) v += __shfl_down(v, off, 64);
    return v;
}

// ==================== MX-FP4 path ====================
// Expanded ±1 fp4 (e2m1 nibbles 0x2/0xA), tiled for 256-row blocks and
// BK=128 steps, fragment-ready for v_mfma_f32_32x32x64_f8f6f4 (FMT=fp4):
//   row r, k-bit k:  bm=r>>8, rt=(r>>5)&7, ri=r&31
//                    s=k>>7, kt=(k>>6)&1, hb=(k>>5)&1
//   chunk(bm,s) = 16KB; offset = ((bm*16+s)*8 + rt)*2048 + kt*1024
//                                + (ri+32*hb)*16 + ((k&31)>>1)
// A 128-row (or 128-col for B) half-block = contiguous 8KB per chunk.

// round-9 expand (verified): 8 rows up-front, one reduction pass, 2 barriers,
// vectorized b128 writeout.
__global__ __launch_bounds__(256) void expand_kernel(const float* __restrict__ x,
                                                     const float* __restrict__ gamma,
                                                     const float* __restrict__ beta,
                                                     const float* __restrict__ w,
                                                     char* __restrict__ Aexp,
                                                     char* __restrict__ Bexp,
                                                     int Mblocks) {
    const int t = threadIdx.x;
    const int wid = t >> 6, lane = t & 63;
    __shared__ float red[4][2 * RPB];
    __shared__ __align__(16) unsigned stg[RPB * 256];  // 8 rows x 1KB, swizzled

    const bool isA = (int)blockIdx.x < Mblocks;
    const int r0 = (isA ? (int)blockIdx.x : ((int)blockIdx.x - Mblocks)) * RPB;
    const float* src = isA ? x : w;

    float gg[8], bb[8];
    if (isA) {
        float4 g0 = ((const float4*)gamma)[t * 2];
        float4 g1 = ((const float4*)gamma)[t * 2 + 1];
        float4 b0 = ((const float4*)beta)[t * 2];
        float4 b1 = ((const float4*)beta)[t * 2 + 1];
        gg[0]=g0.x; gg[1]=g0.y; gg[2]=g0.z; gg[3]=g0.w;
        gg[4]=g1.x; gg[5]=g1.y; gg[6]=g1.z; gg[7]=g1.w;
        bb[0]=b0.x; bb[1]=b0.y; bb[2]=b0.z; bb[3]=b0.w;
        bb[4]=b1.x; bb[5]=b1.y; bb[6]=b1.z; bb[7]=b1.w;
    }

    float vv[RPB][8];
    #pragma unroll
    for (int rr = 0; rr < RPB; ++rr) {
        const float* xr = src + (size_t)(r0 + rr) * DIN;
        float4 v0 = ((const float4*)xr)[t * 2];
        float4 v1 = ((const float4*)xr)[t * 2 + 1];
        vv[rr][0]=v0.x; vv[rr][1]=v0.y; vv[rr][2]=v0.z; vv[rr][3]=v0.w;
        vv[rr][4]=v1.x; vv[rr][5]=v1.y; vv[rr][6]=v1.z; vv[rr][7]=v1.w;
    }

    #pragma unroll
    for (int rr = 0; rr < RPB; ++rr) {
        float s = 0.f, ss = 0.f;
        #pragma unroll
        for (int j = 0; j < 8; ++j) s += vv[rr][j];
        if (isA) {
            #pragma unroll
            for (int j = 0; j < 8; ++j) ss += vv[rr][j] * vv[rr][j];
        }
        s = wave_sum(s);
        if (isA) ss = wave_sum(ss);
        if (lane == 0) { red[wid][rr * 2] = s; red[wid][rr * 2 + 1] = ss; }
    }
    __syncthreads();

    #pragma unroll
    for (int rr = 0; rr < RPB; ++rr) {
        float tot = red[0][rr*2] + red[1][rr*2] + red[2][rr*2] + red[3][rr*2];
        float mu  = tot * (1.f / DIN);
        unsigned word = 0;
        if (isA) {
            float tots = red[0][rr*2+1] + red[1][rr*2+1] + red[2][rr*2+1] + red[3][rr*2+1];
            float var  = tots * (1.f / DIN) - mu * mu;
            float rs   = rsqrtf(var + LN_EPS);
            #pragma unroll
            for (int j = 0; j < 8; ++j) {
                float xn = (vv[rr][j] - mu) * rs * gg[j] + bb[j];
                word |= (xn < 0.f ? 0xAu : 0x2u) << (4 * j);
            }
        } else {
            #pragma unroll
            for (int j = 0; j < 8; ++j)
                word |= ((vv[rr][j] - mu) < 0.f ? 0xAu : 0x2u) << (4 * j);
        }
        stg[rr * 256 + (((t >> 2) ^ rr) << 2) + (t & 3)] = word;
    }
    __syncthreads();

    char* dstbase = isA ? Aexp : Bexp;
    const int bm  = r0 >> 8;
    const int rt  = (r0 >> 5) & 7;
    const int ri0 = r0 & 31;
    #pragma unroll
    for (int i2 = 0; i2 < 2; ++i2) {
        const int u  = i2 * 256 + t;         // 0..511
        const int sc = u >> 5;               // 16 K-chunks
        const int kt = (u >> 4) & 1, hb = (u >> 3) & 1, ri = u & 7;
        const int g  = sc * 4 + kt * 2 + hb; // logical source granule
        uint4 v = *(const uint4*)&stg[ri * 256 + ((g ^ ri) << 2)];
        const size_t doff = (((size_t)(bm * 16 + sc)) * 8 + rt) * 2048 + kt * 1024 +
                            (ri0 + ri + 32 * hb) * 16;
        *(uint4*)(dstbase + doff) = v;
    }
}

// Round-21 gemm: r18 champion geometry (128x128 tile, 4 waves 2x2, 2x2
// subtiles/wave, 3 blocks/CU, A via global_load_lds tri-buffer, B direct
// from L2, L2-resident XCD map, NT stores) with ONE change: WAVE-PRIVATE A
// staging -> ZERO barriers. Each wave stages its OWN 4 KB A region (rt
// groups {2wr, 2wr+1} x kt), duplicating A staging for the 2 waves sharing
// a row-half; no cross-wave LDS dependency, so the per-wave pipeline
// free-runs with only counted vmcnt. LDS = 4 waves x 4KB x 3 bufs = 48 KB.
// Per-wave race audit: buf (s+2)%3 region is wave-private; its step-(s-1)
// ds_reads were issued+awaited (lgkmcnt) before stage(s+2) in program
// order. vmcnt: enter step s with stage(s+1)x4 outstanding; issue B(s)x4
// then stage(s+2)x4; compiler's B-wait also drains stage(s+1); end-of-step
// vmcnt(4) keeps stage(s+2) in flight (tail: vmcnt(0) at s=14).
__global__ __launch_bounds__(256, 3) void fp4gemm_kernel(const char* __restrict__ Aexp,
                                                         const char* __restrict__ Bexp,
                                                         const float* __restrict__ bias,
                                                         const float* __restrict__ alpha,
                                                         float* __restrict__ out,
                                                         int ldc, int nBmX) {
    __shared__ char As[3][16384];         // 4 waves x 4KB, wave-private regions
    const int t = threadIdx.x;
    const int wv = t >> 6, lane = t & 63;
    const int xcd = blockIdx.x & 7;       // round-robin -> this block's XCD
    const int loc = blockIdx.x >> 3;      // index within XCD
    const int bm = xcd * nBmX + (loc % nBmX);  // 128-row band; A-slice L2-resident
    const int bn = loc / nBmX;                 // 128-col band; B L2-resident
    const int wr = wv >> 1, wc = wv & 1;  // 2x2 wave grid, 64x64 per wave

    // 128-row/col half of a 256-block: contiguous 8KB at (bm&1)*8192
    const char* gA = Aexp + (size_t)(bm >> 1) * 262144 + (size_t)(bm & 1) * 8192;
    const char* gB = Bexp + (size_t)(bn >> 1) * 262144 + (size_t)(bn & 1) * 8192 + lane * 16;

    // wave-private stage: rows (wr*2+i)*32, kt 0..1 -> 4 x 1KB into own region
#define STAGE(BUF, S)                                                           \
    {                                                                           \
        _Pragma("unroll")                                                       \
        for (int i2 = 0; i2 < 2; ++i2)                                          \
            _Pragma("unroll")                                                   \
            for (int kt = 0; kt < 2; ++kt) {                                    \
                __builtin_amdgcn_global_load_lds(                               \
                    (const GLOBAL_AS unsigned*)(gA + (size_t)(S) * 16384 +      \
                        (wr * 2 + i2) * 2048 + kt * 1024 + lane * 16),          \
                    (LDS_AS unsigned*)(&As[BUF][wv * 4096 + i2 * 2048 +         \
                        kt * 1024 + lane * 16]), 16, 0, 0);                     \
            }                                                                   \
    }

    f32x16 acc[2][2];
    #pragma unroll
    for (int i = 0; i < 2; ++i)
        #pragma unroll
        for (int j = 0; j < 2; ++j)
            #pragma unroll
            for (int e = 0; e < 16; ++e) acc[i][j][e] = 0.f;

    STAGE(0, 0)
    STAGE(1, 1)
    asm volatile("s_waitcnt vmcnt(4)" ::: "memory");   // my tile-0 A resident

    int c = 0;
    #pragma unroll 1
    for (int s = 0; s < 16; ++s) {
        // B fragments direct from L2 (issued before the s+2 stage so the
        // compiler's B-wait also proves stage(s+1) complete).
        i32x4 bf[2][2];
        #pragma unroll
        for (int kt = 0; kt < 2; ++kt)
            #pragma unroll
            for (int j = 0; j < 2; ++j)
                bf[kt][j] = *(const i32x4*)(gB + (size_t)s * 16384 +
                                            (wc * 2 + j) * 2048 + kt * 1024);
        if (s <= 13) {
            const int nb = (c == 0) ? 2 : c - 1;       // (s+2) % 3
            STAGE(nb, s + 2)
        }
        #pragma unroll
        for (int kt = 0; kt < 2; ++kt) {
            i32x4 a[2];
            #pragma unroll
            for (int i = 0; i < 2; ++i)
                a[i] = *(const i32x4*)&As[c][wv * 4096 + i * 2048 + kt * 1024 + lane * 16];
            i32x8 aa[2], bb2[2];
            #pragma unroll
            for (int i = 0; i < 2; ++i) {
                aa[i][0]=a[i][0]; aa[i][1]=a[i][1]; aa[i][2]=a[i][2]; aa[i][3]=a[i][3];
                aa[i][4]=a[i][0]; aa[i][5]=a[i][1]; aa[i][6]=a[i][2]; aa[i][7]=a[i][3];
                bb2[i][0]=bf[kt][i][0]; bb2[i][1]=bf[kt][i][1];
                bb2[i][2]=bf[kt][i][2]; bb2[i][3]=bf[kt][i][3];
                bb2[i][4]=bf[kt][i][0]; bb2[i][5]=bf[kt][i][1];
                bb2[i][6]=bf[kt][i][2]; bb2[i][7]=bf[kt][i][3];
            }
            __builtin_amdgcn_s_setprio(1);
            #pragma unroll
            for (int i = 0; i < 2; ++i)
                #pragma unroll
                for (int j = 0; j < 2; ++j)
                    acc[i][j] = __builtin_amdgcn_mfma_scale_f32_32x32x64_f8f6f4(
                        aa[i], bb2[j], acc[i][j], 4, 4,      // FMT: fp4 e2m1
                        0, 0x7F7F7F7F, 0, 0x7F7F7F7F);       // scales = 1.0
            __builtin_amdgcn_s_setprio(0);
        }
        if (s == 15) break;
        if (s <= 13) { asm volatile("s_waitcnt vmcnt(4)" ::: "memory"); } // s+1 A in; s+2 in flight
        else         { asm volatile("s_waitcnt vmcnt(0)" ::: "memory"); } // tail drain
        c = (c == 2) ? 0 : c + 1;
    }
#undef STAGE

    // C/D mapping (32x32, dtype-independent): col=lane&31, row=(reg&3)+8*(reg>>2)+4*(lane>>5)
    // Non-temporal stores: streaming output must not evict A/B from L2.
    const int cl = lane & 31;
    const int rb = 4 * (lane >> 5);
    #pragma unroll
    for (int i = 0; i < 2; ++i) {
        #pragma unroll
        for (int j = 0; j < 2; ++j) {
            const int col = bn * 128 + wc * 64 + j * 32 + cl;
            const float bi = bias[col], al = alpha[col];
            const int row0 = bm * 128 + wr * 64 + i * 32 + rb;
            #pragma unroll
            for (int reg = 0; reg < 16; ++reg) {
                const int row = row0 + (reg & 3) + 8 * (reg >> 2);
                __builtin_nontemporal_store((acc[i][j][reg] + bi) * al,
                                            &out[(size_t)row * ldc + col]);
            }
        }
    }
}

// ==================== fallback popcount path (round-3, verified) ====================
__global__ __launch_bounds__(256) void w_pack_kernel(const float* __restrict__ w,
                                                     unsigned* __restrict__ wpk) {
    const int row = blockIdx.x;
    const int t = threadIdx.x;
    const float* wr = w + (size_t)row * DIN;
    float4 v0 = ((const float4*)wr)[t * 2];
    float4 v1 = ((const float4*)wr)[t * 2 + 1];
    float s = v0.x + v0.y + v0.z + v0.w + v1.x + v1.y + v1.z + v1.w;

    __shared__ float red[4];
    float wsum = wave_sum(s);
    int wid = t >> 6, lane = t & 63;
    if (lane == 0) red[wid] = wsum;
    __syncthreads();
    float mu = (red[0] + red[1] + red[2] + red[3]) * (1.f / DIN);

    float vv[8] = {v0.x, v0.y, v0.z, v0.w, v1.x, v1.y, v1.z, v1.w};
    unsigned byte = 0;
    #pragma unroll
    for (int j = 0; j < 8; ++j)
        byte |= ((vv[j] - mu) < 0.f ? 1u : 0u) << j;

    __shared__ unsigned char bytes[256];
    bytes[t] = (unsigned char)byte;
    __syncthreads();
    if (t < 64) {
        unsigned wd = (unsigned)bytes[t * 4] | ((unsigned)bytes[t * 4 + 1] << 8) |
                      ((unsigned)bytes[t * 4 + 2] << 16) | ((unsigned)bytes[t * 4 + 3] << 24);
        wpk[(size_t)row * WPR + t] = wd;
    }
}

__global__ __launch_bounds__(256) void ln_pack_kernel(const float* __restrict__ x,
                                                      const float* __restrict__ gamma,
                                                      const float* __restrict__ beta,
                                                      unsigned* __restrict__ apk) {
    const int row = blockIdx.x;
    const int t = threadIdx.x;
    const float* xr = x + (size_t)row * DIN;
    float4 v0 = ((const float4*)xr)[t * 2];
    float4 v1 = ((const float4*)xr)[t * 2 + 1];
    float s  = v0.x + v0.y + v0.z + v0.w + v1.x + v1.y + v1.z + v1.w;
    float ss = v0.x * v0.x + v0.y * v0.y + v0.z * v0.z + v0.w * v0.w +
               v1.x * v1.x + v1.y * v1.y + v1.z * v1.z + v1.w * v1.w;

    __shared__ float red[8];
    float wsum = wave_sum(s), wssum = wave_sum(ss);
    int wid = t >> 6, lane = t & 63;
    if (lane == 0) { red[wid] = wsum; red[4 + wid] = wssum; }
    __syncthreads();
    float tot  = red[0] + red[1] + red[2] + red[3];
    float tots = red[4] + red[5] + red[6] + red[7];
    float mu  = tot * (1.f / DIN);
    float var = tots * (1.f / DIN) - mu * mu;
    float rs  = rsqrtf(var + LN_EPS);

    float4 g0 = ((const float4*)gamma)[t * 2];
    float4 g1 = ((const float4*)gamma)[t * 2 + 1];
    float4 b0 = ((const float4*)beta)[t * 2];
    float4 b1 = ((const float4*)beta)[t * 2 + 1];
    float vv[8] = {v0.x, v0.y, v0.z, v0.w, v1.x, v1.y, v1.z, v1.w};
    float gg[8] = {g0.x, g0.y, g0.z, g0.w, g1.x, g1.y, g1.z, g1.w};
    float bb[8] = {b0.x, b0.y, b0.z, b0.w, b1.x, b1.y, b1.z, b1.w};
    unsigned byte = 0;
    #pragma unroll
    for (int j = 0; j < 8; ++j) {
        float xn = (vv[j] - mu) * rs * gg[j] + bb[j];
        byte |= (xn < 0.f ? 1u : 0u) << j;
    }

    __shared__ unsigned char bytes[256];
    bytes[t] = (unsigned char)byte;
    __syncthreads();
    if (t < 64) {
        unsigned wd = (unsigned)bytes[t * 4] | ((unsigned)bytes[t * 4 + 1] << 8) |
                      ((unsigned)bytes[t * 4 + 2] << 16) | ((unsigned)bytes[t * 4 + 3] << 24);
        apk[(size_t)row * WPR + t] = wd;
    }
}

__global__ __launch_bounds__(256) void bingemm_kernel(const u64* __restrict__ A,
                                                      const u64* __restrict__ B,
                                                      const float* __restrict__ bias,
                                                      const float* __restrict__ alpha,
                                                      float* __restrict__ out) {
    __shared__ u64 S[2 * 128 * QPR];
    uint4* Sg = (uint4*)S;
    const int t = threadIdx.x;
    const int bn = blockIdx.x, bm = blockIdx.y;

    const uint4* Ag = (const uint4*)(A + (size_t)bm * 128 * QPR);
    #pragma unroll
    for (int i = 0; i < 8; ++i) {
        int id = t + i * 256;
        int row = id >> 4, g = id & 15;
        Sg[(row << 4) + (g ^ (row & 15))] = Ag[id];
    }
    const uint4* Bg = (const uint4*)(B + (size_t)bn * 128 * QPR);
    #pragma unroll
    for (int i = 0; i < 8; ++i) {
        int id = t + i * 256;
        int row = id >> 4, g = id & 15;
        Sg[2048 + (row << 4) + (g ^ (row & 15))] = Bg[id];
    }
    __syncthreads();

    const int tr = t >> 4;
    const int tc = t & 15;
    const ulonglong2* Sq = (const ulonglong2*)S;
    const int abase = tr * GPR;
    const int bbase = 2048 + tc * GPR;

    int acc[8][8] = {};
    u64 a0[8][2], b0[8][2], a1[8][2], b1[8][2];

#define LOADK(KK, AR, BR)                                            \
    {                                                                \
        const int ka = abase + ((KK) ^ tr);                          \
        const int kb = bbase + ((KK) ^ tc);                          \
        _Pragma("unroll")                                            \
        for (int r = 0; r < 8; ++r) {                                \
            ulonglong2 v = Sq[ka + r * 256];                         \
            AR[r][0] = v.x; AR[r][1] = v.y;                          \
        }                                                            \
        _Pragma("unroll")                                            \
        for (int c2 = 0; c2 < 8; ++c2) {                             \
            ulonglong2 v = Sq[kb + c2 * 256];                        \
            BR[c2][0] = v.x; BR[c2][1] = v.y;                        \
        }                                                            \
    }

#define COMPK(AR, BR)                                                \
    {                                                                \
        _Pragma("unroll")                                            \
        for (int r = 0; r < 8; ++r) {                                \
            _Pragma("unroll")                                        \
            for (int c2 = 0; c2 < 8; ++c2) {                         \
                acc[r][c2] += __popcll(AR[r][0] ^ BR[c2][0]);        \
                acc[r][c2] += __popcll(AR[r][1] ^ BR[c2][1]);        \
            }                                                        \
        }                                                            \
    }

    LOADK(0, a0, b0);
    #pragma unroll 1
    for (int kk = 0; kk < 14; kk += 2) {
        LOADK(kk + 1, a1, b1);
        COMPK(a0, b0);
        LOADK(kk + 2, a0, b0);
        COMPK(a1, b1);
    }
    LOADK(15, a1, b1);
    COMPK(a0, b0);
    COMPK(a1, b1);
#undef LOADK
#undef COMPK

    float bi[8], al[8];
    #pragma unroll
    for (int c2 = 0; c2 < 8; ++c2) {
        int col = bn * 128 + tc + 16 * c2;
        bi[c2] = bias[col];
        al[c2] = alpha[col];
    }
    #pragma unroll
    for (int r = 0; r < 8; ++r) {
        const size_t row = (size_t)bm * 128 + tr + 16 * r;
        float* op = out + row * 2048 + bn * 128 + tc;
        #pragma unroll
        for (int c2 = 0; c2 < 8; ++c2)
            op[16 * c2] = ((float)(DIN - 2 * acc[r][c2]) + bi[c2]) * al[c2];
    }
}

extern "C" void kernel_launch(void* const* d_in, const int* in_sizes, int n_in,
                              void* d_out, int out_size, void* d_ws, size_t ws_size,
                              hipStream_t stream) {
    const float* x     = (const float*)d_in[0];
    const float* gamma = (const float*)d_in[1];
    const float* beta  = (const float*)d_in[2];
    const float* w     = (const float*)d_in[3];
    const float* bias  = (const float*)d_in[4];
    const float* alpha = (const float*)d_in[5];
    float* out = (float*)d_out;

    const int M = in_sizes[0] / DIN;          // 16384
    const int N = in_sizes[3] / DIN;          // 2048

    const size_t needA = (size_t)M * (DIN / 2);   // 16.8 MB fp4
    const size_t needB = (size_t)N * (DIN / 2);   // 2 MB fp4

    if (ws_size >= needA + needB && (M % 1024) == 0 && N == 2048) {
        char* Aexp = (char*)d_ws;
        char* Bexp = (char*)d_ws + needA;
        expand_kernel<<<(M + N) / RPB, 256, 0, stream>>>(x, gamma, beta, w,
                                                         Aexp, Bexp, M / RPB);
        const int nBmX = (M / 128) / 8;       // 128-row bands per XCD (16)
        dim3 grid((M / 128) * (N / 128));     // 2048 blocks
        fp4gemm_kernel<<<grid, 256, 0, stream>>>(Aexp, Bexp, bias, alpha, out,
                                                 N, nBmX);
    } else {
        unsigned* apk = (unsigned*)d_ws;
        unsigned* wpk = (unsigned*)((char*)d_ws + (size_t)M * WPR * 4);
        w_pack_kernel<<<N, 256, 0, stream>>>(w, wpk);
        ln_pack_kernel<<<M, 256, 0, stream>>>(x, gamma, beta, apk);
        dim3 grid(N / 128, M / 128);
        bingemm_kernel<<<grid, 256, 0, stream>>>((const u64*)apk, (const u64*)wpk,
                                                 bias, alpha, out);
    }
}

// Round 22
// 80.143 us; speedup vs baseline: 1.0708x; 1.0708x over previous
//
#include <hip/hip_runtime.h>

#define DIN 2048
#define WPR 64            // u32 words per row (2048 bits)
#define QPR 32            // u64 words per row
#define GPR 16            // 16B granules per row
#define RPB 8             // rows per expand block
#define LN_EPS 1e-5f

#define GLOBAL_AS __attribute__((address_space(1)))
#define LDS_AS    __attribute__((address_space(3)))

typedef unsigned long long u64;
typedef int   i32x4  __attribute__((ext_vector_type(4)));
typedef int   i32x8  __attribute__((ext_vector_type(8)));
typedef float f32x16 __attribute__((ext_vector_type(16)));

__device__ inline float wave_sum(float v) {
    #pragma unroll
    for (int off = 32; off; off >>= 1) v += __shfl_down(v, off, 64);
    return v;
}

// ==================== MX-FP4 path ====================
// Expanded ±1 fp4 (e2m1 nibbles 0x2/0xA), tiled for 256-row blocks and
// BK=128 steps, fragment-ready for v_mfma_f32_32x32x64_f8f6f4 (FMT=fp4):
//   row r, k-bit k:  bm=r>>8, rt=(r>>5)&7, ri=r&31
//                    s=k>>7, kt=(k>>6)&1, hb=(k>>5)&1
//   chunk(bm,s) = 16KB; offset = ((bm*16+s)*8 + rt)*2048 + kt*1024
//                                + (ri+32*hb)*16 + ((k&31)>>1)
// A 128-row (or 128-col for B) half-block = contiguous 8KB per chunk.

// round-9 expand (verified): 8 rows up-front, one reduction pass, 2 barriers,
// vectorized b128 writeout.
__global__ __launch_bounds__(256) void expand_kernel(const float* __restrict__ x,
                                                     const float* __restrict__ gamma,
                                                     const float* __restrict__ beta,
                                                     const float* __restrict__ w,
                                                     char* __restrict__ Aexp,
                                                     char* __restrict__ Bexp,
                                                     int Mblocks) {
    const int t = threadIdx.x;
    const int wid = t >> 6, lane = t & 63;
    __shared__ float red[4][2 * RPB];
    __shared__ __align__(16) unsigned stg[RPB * 256];  // 8 rows x 1KB, swizzled

    const bool isA = (int)blockIdx.x < Mblocks;
    const int r0 = (isA ? (int)blockIdx.x : ((int)blockIdx.x - Mblocks)) * RPB;
    const float* src = isA ? x : w;

    float gg[8], bb[8];
    if (isA) {
        float4 g0 = ((const float4*)gamma)[t * 2];
        float4 g1 = ((const float4*)gamma)[t * 2 + 1];
        float4 b0 = ((const float4*)beta)[t * 2];
        float4 b1 = ((const float4*)beta)[t * 2 + 1];
        gg[0]=g0.x; gg[1]=g0.y; gg[2]=g0.z; gg[3]=g0.w;
        gg[4]=g1.x; gg[5]=g1.y; gg[6]=g1.z; gg[7]=g1.w;
        bb[0]=b0.x; bb[1]=b0.y; bb[2]=b0.z; bb[3]=b0.w;
        bb[4]=b1.x; bb[5]=b1.y; bb[6]=b1.z; bb[7]=b1.w;
    }

    float vv[RPB][8];
    #pragma unroll
    for (int rr = 0; rr < RPB; ++rr) {
        const float* xr = src + (size_t)(r0 + rr) * DIN;
        float4 v0 = ((const float4*)xr)[t * 2];
        float4 v1 = ((const float4*)xr)[t * 2 + 1];
        vv[rr][0]=v0.x; vv[rr][1]=v0.y; vv[rr][2]=v0.z; vv[rr][3]=v0.w;
        vv[rr][4]=v1.x; vv[rr][5]=v1.y; vv[rr][6]=v1.z; vv[rr][7]=v1.w;
    }

    #pragma unroll
    for (int rr = 0; rr < RPB; ++rr) {
        float s = 0.f, ss = 0.f;
        #pragma unroll
        for (int j = 0; j < 8; ++j) s += vv[rr][j];
        if (isA) {
            #pragma unroll
            for (int j = 0; j < 8; ++j) ss += vv[rr][j] * vv[rr][j];
        }
        s = wave_sum(s);
        if (isA) ss = wave_sum(ss);
        if (lane == 0) { red[wid][rr * 2] = s; red[wid][rr * 2 + 1] = ss; }
    }
    __syncthreads();

    #pragma unroll
    for (int rr = 0; rr < RPB; ++rr) {
        float tot = red[0][rr*2] + red[1][rr*2] + red[2][rr*2] + red[3][rr*2];
        float mu  = tot * (1.f / DIN);
        unsigned word = 0;
        if (isA) {
            float tots = red[0][rr*2+1] + red[1][rr*2+1] + red[2][rr*2+1] + red[3][rr*2+1];
            float var  = tots * (1.f / DIN) - mu * mu;
            float rs   = rsqrtf(var + LN_EPS);
            #pragma unroll
            for (int j = 0; j < 8; ++j) {
                float xn = (vv[rr][j] - mu) * rs * gg[j] + bb[j];
                word |= (xn < 0.f ? 0xAu : 0x2u) << (4 * j);
            }
        } else {
            #pragma unroll
            for (int j = 0; j < 8; ++j)
                word |= ((vv[rr][j] - mu) < 0.f ? 0xAu : 0x2u) << (4 * j);
        }
        stg[rr * 256 + (((t >> 2) ^ rr) << 2) + (t & 3)] = word;
    }
    __syncthreads();

    char* dstbase = isA ? Aexp : Bexp;
    const int bm  = r0 >> 8;
    const int rt  = (r0 >> 5) & 7;
    const int ri0 = r0 & 31;
    #pragma unroll
    for (int i2 = 0; i2 < 2; ++i2) {
        const int u  = i2 * 256 + t;         // 0..511
        const int sc = u >> 5;               // 16 K-chunks
        const int kt = (u >> 4) & 1, hb = (u >> 3) & 1, ri = u & 7;
        const int g  = sc * 4 + kt * 2 + hb; // logical source granule
        uint4 v = *(const uint4*)&stg[ri * 256 + ((g ^ ri) << 2)];
        const size_t doff = (((size_t)(bm * 16 + sc)) * 8 + rt) * 2048 + kt * 1024 +
                            (ri0 + ri + 32 * hb) * 16;
        *(uint4*)(dstbase + doff) = v;
    }
}

// FINAL gemm (round-18 champion, 80.5 us total): 128x128 tile, 4 waves 2x2,
// 2x2 32x32 subtiles/wave, 3 blocks/CU; A staged via global_load_lds
// tri-buffer (24 KB), B loaded DIRECTLY from L2 into registers (panel is
// L2-resident via the XCD-sliced map); counted vmcnt(2) (stage s+2 stays in
// flight; drain only in tail); NT stores for the streaming output.
// Session evidence: all-direct (-5.5), B-dbuf (-3.4), wave-private-A (-5.3),
// phase-split (0), depth-4 (-1.6) all regress vs this structure.
__global__ __launch_bounds__(256, 3) void fp4gemm_kernel(const char* __restrict__ Aexp,
                                                         const char* __restrict__ Bexp,
                                                         const float* __restrict__ bias,
                                                         const float* __restrict__ alpha,
                                                         float* __restrict__ out,
                                                         int ldc, int nBmX) {
    __shared__ char As[3][8192];
    const int t = threadIdx.x;
    const int wv = t >> 6, lane = t & 63;
    const int xcd = blockIdx.x & 7;       // round-robin -> this block's XCD
    const int loc = blockIdx.x >> 3;      // index within XCD
    const int bm = xcd * nBmX + (loc % nBmX);  // 128-row band; A-slice L2-resident
    const int bn = loc / nBmX;                 // 128-col band; B L2-resident
    const int wr = wv >> 1, wc = wv & 1;  // 2x2 wave grid, 64x64 per wave

    // 128-row/col half of a 256-block: contiguous 8KB at (bm&1)*8192
    const char* gA = Aexp + (size_t)(bm >> 1) * 262144 + (size_t)(bm & 1) * 8192;
    const char* gB = Bexp + (size_t)(bn >> 1) * 262144 + (size_t)(bn & 1) * 8192 + lane * 16;

    // per stage: A 8KB = 8 chunks of 1KB; 2 loads/wave
#define STAGE(BUF, S)                                                           \
    {                                                                           \
        _Pragma("unroll")                                                       \
        for (int i2 = 0; i2 < 2; ++i2) {                                        \
            const int ch = wv * 2 + i2;                                         \
            __builtin_amdgcn_global_load_lds(                                   \
                (const GLOBAL_AS unsigned*)(gA + (size_t)(S) * 16384 + ch * 1024 + lane * 16), \
                (LDS_AS unsigned*)(&As[BUF][ch * 1024]), 16, 0, 0);             \
        }                                                                       \
    }

    f32x16 acc[2][2];
    #pragma unroll
    for (int i = 0; i < 2; ++i)
        #pragma unroll
        for (int j = 0; j < 2; ++j)
            #pragma unroll
            for (int e = 0; e < 16; ++e) acc[i][j][e] = 0.f;

    STAGE(0, 0)
    STAGE(1, 1)
    asm volatile("s_waitcnt vmcnt(2)" ::: "memory");   // tile 0 A resident (mine)
    __builtin_amdgcn_s_barrier();                      // -> everyone's
    asm volatile("" ::: "memory");

    int c = 0;
    #pragma unroll 1
    for (int s = 0; s < 16; ++s) {
        // B fragments direct from L2 -- issued FIRST so the A-stage loads
        // below remain youngest in the vmcnt queue.
        i32x4 bf[2][2];
        #pragma unroll
        for (int kt = 0; kt < 2; ++kt)
            #pragma unroll
            for (int j = 0; j < 2; ++j)
                bf[kt][j] = *(const i32x4*)(gB + (size_t)s * 16384 +
                                            (wc * 2 + j) * 2048 + kt * 1024);
        if (s <= 13) {
            const int nb = (c == 0) ? 2 : c - 1;       // (s+2) % 3
            STAGE(nb, s + 2)                           // issue EARLY (T3)
        }
        #pragma unroll
        for (int kt = 0; kt < 2; ++kt) {
            i32x4 a[2];
            #pragma unroll
            for (int i = 0; i < 2; ++i)
                a[i] = *(const i32x4*)&As[c][(wr * 2 + i) * 2048 + kt * 1024 + lane * 16];
            i32x8 aa[2], bb2[2];
            #pragma unroll
            for (int i = 0; i < 2; ++i) {
                aa[i][0]=a[i][0]; aa[i][1]=a[i][1]; aa[i][2]=a[i][2]; aa[i][3]=a[i][3];
                aa[i][4]=a[i][0]; aa[i][5]=a[i][1]; aa[i][6]=a[i][2]; aa[i][7]=a[i][3];
                bb2[i][0]=bf[kt][i][0]; bb2[i][1]=bf[kt][i][1];
                bb2[i][2]=bf[kt][i][2]; bb2[i][3]=bf[kt][i][3];
                bb2[i][4]=bf[kt][i][0]; bb2[i][5]=bf[kt][i][1];
                bb2[i][6]=bf[kt][i][2]; bb2[i][7]=bf[kt][i][3];
            }
            __builtin_amdgcn_s_setprio(1);
            #pragma unroll
            for (int i = 0; i < 2; ++i)
                #pragma unroll
                for (int j = 0; j < 2; ++j)
                    acc[i][j] = __builtin_amdgcn_mfma_scale_f32_32x32x64_f8f6f4(
                        aa[i], bb2[j], acc[i][j], 4, 4,      // FMT: fp4 e2m1
                        0, 0x7F7F7F7F, 0, 0x7F7F7F7F);       // scales = 1.0
            __builtin_amdgcn_s_setprio(0);
        }
        if (s == 15) break;
        if (s <= 13) { asm volatile("s_waitcnt vmcnt(2)" ::: "memory"); } // s+1 A in; s+2 in flight
        else         { asm volatile("s_waitcnt vmcnt(0)" ::: "memory"); } // tail drain
        __builtin_amdgcn_s_barrier();
        asm volatile("" ::: "memory");
        c = (c == 2) ? 0 : c + 1;
    }
#undef STAGE

    // C/D mapping (32x32, dtype-independent): col=lane&31, row=(reg&3)+8*(reg>>2)+4*(lane>>5)
    // Non-temporal stores: streaming output must not evict A/B from L2.
    const int cl = lane & 31;
    const int rb = 4 * (lane >> 5);
    #pragma unroll
    for (int i = 0; i < 2; ++i) {
        #pragma unroll
        for (int j = 0; j < 2; ++j) {
            const int col = bn * 128 + wc * 64 + j * 32 + cl;
            const float bi = bias[col], al = alpha[col];
            const int row0 = bm * 128 + wr * 64 + i * 32 + rb;
            #pragma unroll
            for (int reg = 0; reg < 16; ++reg) {
                const int row = row0 + (reg & 3) + 8 * (reg >> 2);
                __builtin_nontemporal_store((acc[i][j][reg] + bi) * al,
                                            &out[(size_t)row * ldc + col]);
            }
        }
    }
}

// ==================== fallback popcount path (round-3, verified) ====================
__global__ __launch_bounds__(256) void w_pack_kernel(const float* __restrict__ w,
                                                     unsigned* __restrict__ wpk) {
    const int row = blockIdx.x;
    const int t = threadIdx.x;
    const float* wr = w + (size_t)row * DIN;
    float4 v0 = ((const float4*)wr)[t * 2];
    float4 v1 = ((const float4*)wr)[t * 2 + 1];
    float s = v0.x + v0.y + v0.z + v0.w + v1.x + v1.y + v1.z + v1.w;

    __shared__ float red[4];
    float wsum = wave_sum(s);
    int wid = t >> 6, lane = t & 63;
    if (lane == 0) red[wid] = wsum;
    __syncthreads();
    float mu = (red[0] + red[1] + red[2] + red[3]) * (1.f / DIN);

    float vv[8] = {v0.x, v0.y, v0.z, v0.w, v1.x, v1.y, v1.z, v1.w};
    unsigned byte = 0;
    #pragma unroll
    for (int j = 0; j < 8; ++j)
        byte |= ((vv[j] - mu) < 0.f ? 1u : 0u) << j;

    __shared__ unsigned char bytes[256];
    bytes[t] = (unsigned char)byte;
    __syncthreads();
    if (t < 64) {
        unsigned wd = (unsigned)bytes[t * 4] | ((unsigned)bytes[t * 4 + 1] << 8) |
                      ((unsigned)bytes[t * 4 + 2] << 16) | ((unsigned)bytes[t * 4 + 3] << 24);
        wpk[(size_t)row * WPR + t] = wd;
    }
}

__global__ __launch_bounds__(256) void ln_pack_kernel(const float* __restrict__ x,
                                                      const float* __restrict__ gamma,
                                                      const float* __restrict__ beta,
                                                      unsigned* __restrict__ apk) {
    const int row = blockIdx.x;
    const int t = threadIdx.x;
    const float* xr = x + (size_t)row * DIN;
    float4 v0 = ((const float4*)xr)[t * 2];
    float4 v1 = ((const float4*)xr)[t * 2 + 1];
    float s  = v0.x + v0.y + v0.z + v0.w + v1.x + v1.y + v1.z + v1.w;
    float ss = v0.x * v0.x + v0.y * v0.y + v0.z * v0.z + v0.w * v0.w +
               v1.x * v1.x + v1.y * v1.y + v1.z * v1.z + v1.w * v1.w;

    __shared__ float red[8];
    float wsum = wave_sum(s), wssum = wave_sum(ss);
    int wid = t >> 6, lane = t & 63;
    if (lane == 0) { red[wid] = wsum; red[4 + wid] = wssum; }
    __syncthreads();
    float tot  = red[0] + red[1] + red[2] + red[3];
    float tots = red[4] + red[5] + red[6] + red[7];
    float mu  = tot * (1.f / DIN);
    float var = tots * (1.f / DIN) - mu * mu;
    float rs  = rsqrtf(var + LN_EPS);

    float4 g0 = ((const float4*)gamma)[t * 2];
    float4 g1 = ((const float4*)gamma)[t * 2 + 1];
    float4 b0 = ((const float4*)beta)[t * 2];
    float4 b1 = ((const float4*)beta)[t * 2 + 1];
    float vv[8] = {v0.x, v0.y, v0.z, v0.w, v1.x, v1.y, v1.z, v1.w};
    float gg[8] = {g0.x, g0.y, g0.z, g0.w, g1.x, g1.y, g1.z, g1.w};
    float bb[8] = {b0.x, b0.y, b0.z, b0.w, b1.x, b1.y, b1.z, b1.w};
    unsigned byte = 0;
    #pragma unroll
    for (int j = 0; j < 8; ++j) {
        float xn = (vv[j] - mu) * rs * gg[j] + bb[j];
        byte |= (xn < 0.f ? 1u : 0u) << j;
    }

    __shared__ unsigned char bytes[256];
    bytes[t] = (unsigned char)byte;
    __syncthreads();
    if (t < 64) {
        unsigned wd = (unsigned)bytes[t * 4] | ((unsigned)bytes[t * 4 + 1] << 8) |
                      ((unsigned)bytes[t * 4 + 2] << 16) | ((unsigned)bytes[t * 4 + 3] << 24);
        apk[(size_t)row * WPR + t] = wd;
    }
}

__global__ __launch_bounds__(256) void bingemm_kernel(const u64* __restrict__ A,
                                                      const u64* __restrict__ B,
                                                      const float* __restrict__ bias,
                                                      const float* __restrict__ alpha,
                                                      float* __restrict__ out) {
    __shared__ u64 S[2 * 128 * QPR];
    uint4* Sg = (uint4*)S;
    const int t = threadIdx.x;
    const int bn = blockIdx.x, bm = blockIdx.y;

    const uint4* Ag = (const uint4*)(A + (size_t)bm * 128 * QPR);
    #pragma unroll
    for (int i = 0; i < 8; ++i) {
        int id = t + i * 256;
        int row = id >> 4, g = id & 15;
        Sg[(row << 4) + (g ^ (row & 15))] = Ag[id];
    }
    const uint4* Bg = (const uint4*)(B + (size_t)bn * 128 * QPR);
    #pragma unroll
    for (int i = 0; i < 8; ++i) {
        int id = t + i * 256;
        int row = id >> 4, g = id & 15;
        Sg[2048 + (row << 4) + (g ^ (row & 15))] = Bg[id];
    }
    __syncthreads();

    const int tr = t >> 4;
    const int tc = t & 15;
    const ulonglong2* Sq = (const ulonglong2*)S;
    const int abase = tr * GPR;
    const int bbase = 2048 + tc * GPR;

    int acc[8][8] = {};
    u64 a0[8][2], b0[8][2], a1[8][2], b1[8][2];

#define LOADK(KK, AR, BR)                                            \
    {                                                                \
        const int ka = abase + ((KK) ^ tr);                          \
        const int kb = bbase + ((KK) ^ tc);                          \
        _Pragma("unroll")                                            \
        for (int r = 0; r < 8; ++r) {                                \
            ulonglong2 v = Sq[ka + r * 256];                         \
            AR[r][0] = v.x; AR[r][1] = v.y;                          \
        }                                                            \
        _Pragma("unroll")                                            \
        for (int c2 = 0; c2 < 8; ++c2) {                             \
            ulonglong2 v = Sq[kb + c2 * 256];                        \
            BR[c2][0] = v.x; BR[c2][1] = v.y;                        \
        }                                                            \
    }

#define COMPK(AR, BR)                                                \
    {                                                                \
        _Pragma("unroll")                                            \
        for (int r = 0; r < 8; ++r) {                                \
            _Pragma("unroll")                                        \
            for (int c2 = 0; c2 < 8; ++c2) {                         \
                acc[r][c2] += __popcll(AR[r][0] ^ BR[c2][0]);        \
                acc[r][c2] += __popcll(AR[r][1] ^ BR[c2][1]);        \
            }                                                        \
        }                                                            \
    }

    LOADK(0, a0, b0);
    #pragma unroll 1
    for (int kk = 0; kk < 14; kk += 2) {
        LOADK(kk + 1, a1, b1);
        COMPK(a0, b0);
        LOADK(kk + 2, a0, b0);
        COMPK(a1, b1);
    }
    LOADK(15, a1, b1);
    COMPK(a0, b0);
    COMPK(a1, b1);
#undef LOADK
#undef COMPK

    float bi[8], al[8];
    #pragma unroll
    for (int c2 = 0; c2 < 8; ++c2) {
        int col = bn * 128 + tc + 16 * c2;
        bi[c2] = bias[col];
        al[c2] = alpha[col];
    }
    #pragma unroll
    for (int r = 0; r < 8; ++r) {
        const size_t row = (size_t)bm * 128 + tr + 16 * r;
        float* op = out + row * 2048 + bn * 128 + tc;
        #pragma unroll
        for (int c2 = 0; c2 < 8; ++c2)
            op[16 * c2] = ((float)(DIN - 2 * acc[r][c2]) + bi[c2]) * al[c2];
    }
}

extern "C" void kernel_launch(void* const* d_in, const int* in_sizes, int n_in,
                              void* d_out, int out_size, void* d_ws, size_t ws_size,
                              hipStream_t stream) {
    const float* x     = (const float*)d_in[0];
    const float* gamma = (const float*)d_in[1];
    const float* beta  = (const float*)d_in[2];
    const float* w     = (const float*)d_in[3];
    const float* bias  = (const float*)d_in[4];
    const float* alpha = (const float*)d_in[5];
    float* out = (float*)d_out;

    const int M = in_sizes[0] / DIN;          // 16384
    const int N = in_sizes[3] / DIN;          // 2048

    const size_t needA = (size_t)M * (DIN / 2);   // 16.8 MB fp4
    const size_t needB = (size_t)N * (DIN / 2);   // 2 MB fp4

    if (ws_size >= needA + needB && (M % 1024) == 0 && N == 2048) {
        char* Aexp = (char*)d_ws;
        char* Bexp = (char*)d_ws + needA;
        expand_kernel<<<(M + N) / RPB, 256, 0, stream>>>(x, gamma, beta, w,
                                                         Aexp, Bexp, M / RPB);
        const int nBmX = (M / 128) / 8;       // 128-row bands per XCD (16)
        dim3 grid((M / 128) * (N / 128));     // 2048 blocks
        fp4gemm_kernel<<<grid, 256, 0, stream>>>(Aexp, Bexp, bias, alpha, out,
                                                 N, nBmX);
    } else {
        unsigned* apk = (unsigned*)d_ws;
        unsigned* wpk = (unsigned*)((char*)d_ws + (size_t)M * WPR * 4);
        w_pack_kernel<<<N, 256, 0, stream>>>(w, wpk);
        ln_pack_kernel<<<M, 256, 0, stream>>>(x, gamma, beta, apk);
        dim3 grid(N / 128, M / 128);
        bingemm_kernel<<<grid, 256, 0, stream>>>((const u64*)apk, (const u64*)wpk,
                                                 bias, alpha, out);
    }
}